// Round 17
// baseline (389.264 us; speedup 1.0000x reference)
//
#include <hip/hip_runtime.h>
#include <hip/hip_cooperative_groups.h>
#include <math.h>

namespace cg = cooperative_groups;

#define HW    16384
#define WID   128
#define NB    4
// output section offsets (floats)
#define OFF_U 3932160
#define OFF_L 4259840
#define OFF_F 4456448

#define TCH   24
#define TROW  132
#define T6_N  (6*TROW*TCH)        // 19008 shorts
#define WG_ELEMS   (9*32*TCH)     // 6912 shorts
#define WC_ELEMS   (9*16*TCH)     // 3456 shorts
#define LDS_N (T6_N + WG_ELEMS)   // 25920 shorts = 51.84 KB (union max)

typedef __attribute__((ext_vector_type(8))) short  short8_t;
typedef __attribute__((ext_vector_type(4))) float  float4_t;

__device__ __forceinline__ float sig_(float x)  { return 1.f/(1.f+__expf(-x)); }
__device__ __forceinline__ float tanh_(float x) { float e=__expf(2.f*x); return 1.f - 2.f/(e+1.f); }
__device__ __forceinline__ unsigned pk2bf(float a, float b){
  unsigned r;
  asm("v_cvt_pk_bf16_f32 %0, %1, %2" : "=v"(r) : "v"(a), "v"(b));
  return r;
}
__device__ __forceinline__ float bf2f(unsigned short s){
  return __uint_as_float(((unsigned)s) << 16);
}
__device__ __forceinline__ int swz1536(int bi){ return (bi & 7)*192 + (bi >> 3); }
__device__ __forceinline__ int swz768 (int bi){ return (bi & 7)*96  + (bi >> 3); }

struct KArgs {
  const float *hn, *pnn, *xp;
  const float *Wdau, *bdau, *Wdal, *bdal;
  const float *Wd1, *s1v, *t1v, *Wd2, *s2v, *t2v;
  const float *Wa0, *Wa1, *Wa2, *Wa3, *Wa4, *Wa5, *batt;
  const float *Wp, *ps, *pt;
  const float *Wg, *bg, *Wc, *bc;
  float* out;
  unsigned *msg, *rh, *u;
};

// ===========================================================================
// Phase bodies as __device__ functions operating on a shared LDS region.
// Bodies are logically identical to the round-16 proven kernels.
// ===========================================================================
__device__ void phaseA_att(const KArgs& A, unsigned short* L, int item)
{
  unsigned short* xl  = L;            // 256*24
  unsigned short* hl  = L + 6144;     // 256*24
  unsigned short* wl1 = L + 12288;    // 32*24
  unsigned short* wl2 = L + 13056;    // 16*24
  const int tid = threadIdx.x;

  const int bi    = swz1536(item);
  const int n     = bi >> 8;
  const int chunk = bi & 255;
  const int b     = chunk >> 6;
  const int pixbase = (chunk & 63) * 256;
  const int pix   = pixbase + tid;

  short8_t zz = {0,0,0,0,0,0,0,0};
#pragma unroll
  for (int it=0; it<3; ++it) *reinterpret_cast<short8_t*>(&xl[tid*8 + it*2048]) = zz;
#pragma unroll
  for (int it=0; it<3; ++it) *reinterpret_cast<short8_t*>(&hl[tid*8 + it*2048]) = zz;
  if (tid < 96)  *reinterpret_cast<short8_t*>(&wl1[tid*8]) = zz;
  if (tid < 48)  *reinterpret_cast<short8_t*>(&wl2[tid*8]) = zz;
  __syncthreads();

  if (tid < 200){
    int o = tid/10, chp = tid - o*10;
    float s = A.s1v[o];
    *reinterpret_cast<unsigned*>(&wl1[o*TCH + 2*chp]) =
        pk2bf(A.Wd1[o*20 + 2*chp]*s, A.Wd1[o*20 + 2*chp+1]*s);
  } else if (tid < 300){
    int e = tid - 200;
    int o = e/10, chp = e - o*10;
    float s = A.s2v[o];
    *reinterpret_cast<unsigned*>(&wl2[o*TCH + 2*chp]) =
        pk2bf(A.Wd2[o*20 + 2*chp]*s, A.Wd2[o*20 + 2*chp+1]*s);
  }

  float h[10];
  float a;
  if (n < 4){
#pragma unroll
    for (int c=0;c<10;c++) h[c] = A.hn[(b*10+c)*HW + pix];
    float v[5]; float mx = -1e30f;
#pragma unroll
    for (int o=0;o<5;o++){
      float t = A.bdau[o];
#pragma unroll
      for (int c=0;c<10;c++) t += A.Wdau[o*10+c]*h[c];
      if (n==0) A.out[OFF_U + (b*5+o)*HW + pix] = t;
      v[o]=t; mx = fmaxf(mx,t);
    }
    float s=0.f;
#pragma unroll
    for (int o=0;o<5;o++){ v[o]=__expf(v[o]-mx); s+=v[o]; }
    a = v[n+1]/s;
  } else {
#pragma unroll
    for (int c=0;c<10;c++) h[c] = A.hn[((NB+b)*10+c)*HW + pix];
    float v[3]; float mx = -1e30f;
#pragma unroll
    for (int o=0;o<3;o++){
      float t = A.bdal[o];
#pragma unroll
      for (int c=0;c<10;c++) t += A.Wdal[o*10+c]*h[c];
      if (n==4) A.out[OFF_L + (b*3+o)*HW + pix] = t;
      v[o]=t; mx = fmaxf(mx,t);
    }
    float s=0.f;
#pragma unroll
    for (int o=0;o<3;o++){ v[o]=__expf(v[o]-mx); s+=v[o]; }
    a = v[n-3]/s;
  }

  float child[10];
#pragma unroll
  for (int c=0;c<10;c++) child[c] = A.pnn[((n*NB+b)*10+c)*HW + pix];

  float af = A.batt[n];
  if (n==0){
#pragma unroll
    for (int c=0;c<10;c++) af += A.Wa0[c]*A.pnn[((1*NB+b)*10+c)*HW+pix];
  } else if (n==1){
#pragma unroll
    for (int c=0;c<10;c++){
      af += A.Wa1[c]   *A.pnn[((0*NB+b)*10+c)*HW+pix];
      af += A.Wa1[10+c]*A.pnn[((2*NB+b)*10+c)*HW+pix];
      af += A.Wa1[20+c]*A.pnn[((3*NB+b)*10+c)*HW+pix];
      af += A.Wa1[30+c]*A.pnn[((4*NB+b)*10+c)*HW+pix];
    }
  } else if (n==2){
#pragma unroll
    for (int c=0;c<10;c++) af += A.Wa2[c]*A.pnn[((1*NB+b)*10+c)*HW+pix];
  } else if (n==3){
#pragma unroll
    for (int c=0;c<10;c++) af += A.Wa3[c]*A.pnn[((1*NB+b)*10+c)*HW+pix];
  } else if (n==4){
#pragma unroll
    for (int c=0;c<10;c++){
      af += A.Wa4[c]   *A.pnn[((1*NB+b)*10+c)*HW+pix];
      af += A.Wa4[10+c]*A.pnn[((5*NB+b)*10+c)*HW+pix];
    }
  } else {
#pragma unroll
    for (int c=0;c<10;c++) af += A.Wa5[c]*A.pnn[((4*NB+b)*10+c)*HW+pix];
  }
  A.out[OFF_F + (n*NB+b)*HW + pix] = sig_(af);

#pragma unroll
  for (int p=0;p<5;p++)
    *reinterpret_cast<unsigned*>(&xl[tid*TCH + 2*p])      = pk2bf(h[2*p]*a, h[2*p+1]*a);
#pragma unroll
  for (int p=0;p<5;p++)
    *reinterpret_cast<unsigned*>(&xl[tid*TCH + 10 + 2*p]) = pk2bf(child[2*p], child[2*p+1]);
  __syncthreads();

  const int l  = tid & 63;
  const int w  = tid >> 6;
  const int lr = l & 15;
  const int lk = l >> 4;

  short8_t wa0 = (lk<3) ? *reinterpret_cast<const short8_t*>(&wl1[lr*TCH      + lk*8]) : zz;
  short8_t wa1 = (lk<3) ? *reinterpret_cast<const short8_t*>(&wl1[(16+lr)*TCH + lk*8]) : zz;
  float t1a[4], t1b[4];
#pragma unroll
  for (int j=0;j<4;j++){
    t1a[j] = A.t1v[lk*4 + j];
    int o1 = 16 + lk*4 + j;
    t1b[j] = (o1 < 20) ? A.t1v[o1] : 0.f;
  }

#pragma unroll
  for (int t=0; t<4; ++t){
    const int tile = w*4 + t;
    short8_t bf = (lk<3) ? *reinterpret_cast<const short8_t*>(&xl[(tile*16+lr)*TCH + lk*8]) : zz;
    float4_t a0 = {0.f,0.f,0.f,0.f}, a1 = {0.f,0.f,0.f,0.f};
    a0 = __builtin_amdgcn_mfma_f32_16x16x32_bf16(wa0, bf, a0, 0,0,0);
    a1 = __builtin_amdgcn_mfma_f32_16x16x32_bf16(wa1, bf, a1, 0,0,0);
    const int rowb = (tile*16+lr)*TCH;
#pragma unroll
    for (int jp=0; jp<2; ++jp){
      float v0 = fmaxf(a0[2*jp]   + t1a[2*jp],   0.f);
      float v1 = fmaxf(a0[2*jp+1] + t1a[2*jp+1], 0.f);
      *reinterpret_cast<unsigned*>(&hl[rowb + lk*4 + 2*jp]) = pk2bf(v0, v1);
    }
    if (lk == 0){
#pragma unroll
      for (int jp=0; jp<2; ++jp){
        float v0 = fmaxf(a1[2*jp]   + t1b[2*jp],   0.f);
        float v1 = fmaxf(a1[2*jp+1] + t1b[2*jp+1], 0.f);
        *reinterpret_cast<unsigned*>(&hl[rowb + 16 + 2*jp]) = pk2bf(v0, v1);
      }
    }
  }
  __syncthreads();

  short8_t wa2 = (lk<3) ? *reinterpret_cast<const short8_t*>(&wl2[lr*TCH + lk*8]) : zz;
  float t2a[4];
#pragma unroll
  for (int j=0;j<4;j++){
    int o = lk*4 + j;
    t2a[j] = (o < 10) ? A.t2v[o] : 0.f;
  }

#pragma unroll
  for (int t=0; t<4; ++t){
    const int tile = w*4 + t;
    short8_t bf = (lk<3) ? *reinterpret_cast<const short8_t*>(&hl[(tile*16+lr)*TCH + lk*8]) : zz;
    float4_t c = {0.f,0.f,0.f,0.f};
    c = __builtin_amdgcn_mfma_f32_16x16x32_bf16(wa2, bf, c, 0,0,0);
    const int pixT = pixbase + tile*16 + lr;
#pragma unroll
    for (int jp=0; jp<2; ++jp){
      const int o0 = lk*4 + 2*jp;
      if (o0 < 10){
        float v0 = fmaxf(c[2*jp]   + t2a[2*jp],   0.f);
        float v1 = fmaxf(c[2*jp+1] + t2a[2*jp+1], 0.f);
        A.msg[((size_t)((n*NB+b)*5 + (o0>>1)))*HW + pixT] = pk2bf(v0, v1);
      }
    }
  }
}

__device__ void phaseB_proj(const KArgs& A, unsigned short* wlds, int item)
{
  const int tid = threadIdx.x;

#pragma unroll
  for (int it=0; it<16; ++it){
    const int e = tid + it*256;
    const int row = e >> 6, q = e & 63;
    uint2 pk; pk.x = 0u; pk.y = 0u;
    if (row < 60){
      const float s = A.ps[row];
      float4 wv = *reinterpret_cast<const float4*>(A.Wp + row*256 + q*4);
      pk.x = pk2bf(wv.x*s, wv.y*s);
      pk.y = pk2bf(wv.z*s, wv.w*s);
    }
    *reinterpret_cast<uint2*>(&wlds[row*264 + q*4]) = pk;
  }
  __syncthreads();

  const int l  = tid & 63;
  const int w  = tid >> 6;
  const int lr = l & 15;
  const int lk = l >> 4;

  const int tile = item*4 + w;
  const int P    = tile*16;
  const int b    = P >> 14;
  const int pixb = P & 16383;
  const int px   = pixb + lr;

  const float* xb = A.xp + (size_t)(b*256)*HW + px;
  float v[64];
#pragma unroll
  for (int ks=0; ks<8; ++ks)
#pragma unroll
    for (int j=0; j<8; ++j)
      v[ks*8+j] = xb[(size_t)(ks*32 + lk*8 + j)*HW];

  short8_t bf[8];
#pragma unroll
  for (int ks=0; ks<8; ++ks){
    union { short8_t s; unsigned u[4]; } bu;
#pragma unroll
    for (int jp=0; jp<4; ++jp)
      bu.u[jp] = pk2bf(v[ks*8+2*jp], v[ks*8+2*jp+1]);
    bf[ks] = bu.s;
  }

  float4_t acc[4];
#pragma unroll
  for (int nf=0;nf<4;nf++){ acc[nf][0]=0.f; acc[nf][1]=0.f; acc[nf][2]=0.f; acc[nf][3]=0.f; }

#pragma unroll
  for (int ks=0; ks<8; ++ks){
#pragma unroll
    for (int nf=0; nf<4; ++nf){
      short8_t wa = *reinterpret_cast<const short8_t*>(&wlds[(nf*16+lr)*264 + ks*32 + lk*8]);
      acc[nf] = __builtin_amdgcn_mfma_f32_16x16x32_bf16(wa, bf[ks], acc[nf], 0,0,0);
    }
  }

#pragma unroll
  for (int nf=0;nf<4;nf++){
#pragma unroll
    for (int jp=0;jp<2;jp++){
      const int row0 = nf*16 + lk*4 + 2*jp;
      if (row0 < 60){
        const unsigned nn = (unsigned)row0 / 10u;
        const int o = row0 - (int)nn*10;
        float att = A.out[OFF_F + (nn*NB+b)*HW + pixb + lr];
        float f   = 2.f - att;
        float v0 = fmaxf(f*acc[nf][2*jp]   + A.pt[row0],   0.f);
        float v1 = fmaxf(f*acc[nf][2*jp+1] + A.pt[row0+1], 0.f);
        size_t idx = ((size_t)((nn*NB+b)*5 + (o>>1)))*HW + pixb + lr;
        unsigned old = A.msg[idx];
        float d0 = bf2f((unsigned short)(old & 0xffffu)) + v0;
        float d1 = bf2f((unsigned short)(old >> 16))     + v1;
        A.msg[idx] = pk2bf(d0, d1);
      }
    }
  }
}

__device__ void phaseC_gates(const KArgs& A, unsigned short* L, int item)
{
  unsigned short* tl = L;
  unsigned short* wl = L + T6_N;
  const int tid = threadIdx.x;

  const int bi = swz768(item);
  const int n  = bi >> 7;
  const int b  = (bi >> 5) & 3;
  const int y0 = (bi & 31) * 4;

  const int base_nb  = (n*NB+b)*10;
  const int base_nb5 = (n*NB+b)*5;
  const float* pb = A.pnn + (size_t)base_nb*HW;

  short8_t zz = {0,0,0,0,0,0,0,0};
#pragma unroll
  for (int it=0; it<10; ++it){
    const int e = tid*8 + it*2048;
    if (e < T6_N) *reinterpret_cast<short8_t*>(&tl[e]) = zz;
  }
#pragma unroll
  for (int it=0; it<4; ++it){
    const int e = tid*8 + it*2048;
    if (e < WG_ELEMS) *reinterpret_cast<short8_t*>(&wl[e]) = zz;
  }
  __syncthreads();

  const float* Wn = A.Wg + n*3600;
#pragma unroll
  for (int it=0; it<8; ++it){
    const int e = tid + it*256;
    if (e < 1800){
      int sh = e/200, rem = e - sh*200, o = rem/10, chp = rem - o*10;
      float w0 = Wn[o*180 + (2*chp  )*9 + sh];
      float w1 = Wn[o*180 + (2*chp+1)*9 + sh];
      *reinterpret_cast<unsigned*>(&wl[(sh*32+o)*TCH + 2*chp]) = pk2bf(w0, w1);
    }
  }
#pragma unroll
  for (int it=0; it<30; ++it){
    const int e = tid + it*256;
    int row = e/1280, rem = e - row*1280, chp = rem>>7, x = rem&127;
    int yy = y0 - 1 + row;
    if ((unsigned)yy < 128u){
      unsigned pk;
      if (chp < 5){
        pk = A.msg[((size_t)(base_nb5 + chp))*HW + yy*WID + x];
      } else {
        const float* s0 = pb + (size_t)(2*chp-10)*HW;
        pk = pk2bf(s0[yy*WID + x], s0[HW + yy*WID + x]);
      }
      *reinterpret_cast<unsigned*>(&tl[(row*TROW + x+1)*TCH + 2*chp]) = pk;
    }
  }
  __syncthreads();

  const int l  = tid & 63;
  const int w  = tid >> 6;
  const int lr = l & 15;
  const int lk = l >> 4;

  short8_t wa0[9], wa1[9];
#pragma unroll
  for (int sh=0; sh<9; sh++){
    wa0[sh] = (lk<3) ? *reinterpret_cast<const short8_t*>(&wl[(sh*32 +      lr)*TCH + lk*8]) : zz;
    wa1[sh] = (lk<3) ? *reinterpret_cast<const short8_t*>(&wl[(sh*32 + 16 + lr)*TCH + lk*8]) : zz;
  }
  float bs0[4], bs1[4];
#pragma unroll
  for (int j=0;j<4;j++){
    int o = lk*4 + j;
    bs0[j] = A.bg[n*20 + o];
    int o1 = 16 + lk*4 + j;
    bs1[j] = (o1 < 20) ? A.bg[n*20 + o1] : 0.f;
  }

  for (int t=0; t<8; ++t){
    const int tile  = w*8 + t;
    const int row_t = tile >> 3;
    const int xloc  = (tile & 7) * 16;

    float4_t a0 = {0.f,0.f,0.f,0.f}, a1 = {0.f,0.f,0.f,0.f};
#pragma unroll
    for (int sh=0; sh<9; sh++){
      const int dy = sh/3, dx = sh - dy*3;
      const int addr = ((row_t + dy)*TROW + (xloc + lr + dx))*TCH + lk*8;
      short8_t bf = (lk<3) ? *reinterpret_cast<const short8_t*>(&tl[addr]) : zz;
      a0 = __builtin_amdgcn_mfma_f32_16x16x32_bf16(wa0[sh], bf, a0, 0,0,0);
      a1 = __builtin_amdgcn_mfma_f32_16x16x32_bf16(wa1[sh], bf, a1, 0,0,0);
    }

    const int pix = (y0 + row_t)*WID + xloc + lr;
#pragma unroll
    for (int jp=0; jp<2; ++jp){
      const int j0 = 2*jp;
      const int o  = lk*4 + j0;
      float g0 = sig_(a0[j0]   + bs0[j0]);
      float g1 = sig_(a0[j0+1] + bs0[j0+1]);
      if (o < 10){
        float h0 = pb[(size_t)o*HW + pix];
        float h1 = pb[(size_t)(o+1)*HW + pix];
        A.rh[((size_t)(base_nb5 + (o>>1)))*HW + pix] = pk2bf(g0*h0, g1*h1);
      } else {
        A.u[((size_t)(base_nb5 + ((o-10)>>1)))*HW + pix] = pk2bf(g0, g1);
      }
    }
    if (lk == 0){
#pragma unroll
      for (int jp=0; jp<2; ++jp){
        const int j0 = 2*jp;
        const int o1 = 16 + j0;
        float g0 = sig_(a1[j0]   + bs1[j0]);
        float g1 = sig_(a1[j0+1] + bs1[j0+1]);
        A.u[((size_t)(base_nb5 + ((o1-10)>>1)))*HW + pix] = pk2bf(g0, g1);
      }
    }
  }
}

__device__ void phaseD_out(const KArgs& A, unsigned short* L, int item)
{
  unsigned short* tl = L;
  unsigned short* wl = L + T6_N;
  const int tid = threadIdx.x;

  const int bi = swz768(item);
  const int n  = bi >> 7;
  const int b  = (bi >> 5) & 3;
  const int y0 = (bi & 31) * 4;

  const int base_nb  = (n*NB+b)*10;
  const int base_nb5 = (n*NB+b)*5;
  const float* pb = A.pnn + (size_t)base_nb*HW;

  short8_t zz = {0,0,0,0,0,0,0,0};
#pragma unroll
  for (int it=0; it<10; ++it){
    const int e = tid*8 + it*2048;
    if (e < T6_N) *reinterpret_cast<short8_t*>(&tl[e]) = zz;
  }
#pragma unroll
  for (int it=0; it<2; ++it){
    const int e = tid*8 + it*2048;
    if (e < WC_ELEMS) *reinterpret_cast<short8_t*>(&wl[e]) = zz;
  }
  __syncthreads();

  const float* Wn = A.Wc + n*1800;
#pragma unroll
  for (int it=0; it<4; ++it){
    const int e = tid + it*256;
    if (e < 900){
      int sh = e/100, rem = e - sh*100, o = rem/10, chp = rem - o*10;
      float w0 = Wn[o*180 + (2*chp  )*9 + sh];
      float w1 = Wn[o*180 + (2*chp+1)*9 + sh];
      *reinterpret_cast<unsigned*>(&wl[(sh*16+o)*TCH + 2*chp]) = pk2bf(w0, w1);
    }
  }
#pragma unroll
  for (int it=0; it<30; ++it){
    const int e = tid + it*256;
    int row = e/1280, rem = e - row*1280, chp = rem>>7, x = rem&127;
    int yy = y0 - 1 + row;
    if ((unsigned)yy < 128u){
      unsigned pk;
      if (chp < 5){
        pk = A.msg[((size_t)(base_nb5 + chp))*HW + yy*WID + x];
      } else {
        pk = A.rh[((size_t)(base_nb5 + (chp-5)))*HW + yy*WID + x];
      }
      *reinterpret_cast<unsigned*>(&tl[(row*TROW + x+1)*TCH + 2*chp]) = pk;
    }
  }
  __syncthreads();

  const int l  = tid & 63;
  const int w  = tid >> 6;
  const int lr = l & 15;
  const int lk = l >> 4;

  short8_t wa[9];
#pragma unroll
  for (int sh=0; sh<9; sh++)
    wa[sh] = (lk<3) ? *reinterpret_cast<const short8_t*>(&wl[(sh*16 + lr)*TCH + lk*8]) : zz;

  float bs[4];
#pragma unroll
  for (int j=0;j<4;j++){
    int o = lk*4 + j;
    bs[j] = (o < 10) ? A.bc[n*10 + o] : 0.f;
  }

  for (int t=0; t<8; ++t){
    const int tile  = w*8 + t;
    const int row_t = tile >> 3;
    const int xloc  = (tile & 7) * 16;

    float4_t a0 = {0.f,0.f,0.f,0.f};
#pragma unroll
    for (int sh=0; sh<9; sh++){
      const int dy = sh/3, dx = sh - dy*3;
      const int addr = ((row_t + dy)*TROW + (xloc + lr + dx))*TCH + lk*8;
      short8_t bf = (lk<3) ? *reinterpret_cast<const short8_t*>(&tl[addr]) : zz;
      a0 = __builtin_amdgcn_mfma_f32_16x16x32_bf16(wa[sh], bf, a0, 0,0,0);
    }

    const int pix = (y0 + row_t)*WID + xloc + lr;
#pragma unroll
    for (int jp=0; jp<2; ++jp){
      const int j0 = 2*jp;
      const int o  = lk*4 + j0;
      if (o < 10){
        unsigned up = A.u[((size_t)(base_nb5 + (o>>1)))*HW + pix];
        float u0 = bf2f((unsigned short)(up & 0xffffu));
        float u1 = bf2f((unsigned short)(up >> 16));
        float h0 = pb[(size_t)o*HW + pix];
        float h1 = pb[(size_t)(o+1)*HW + pix];
        float c0 = tanh_(a0[j0]   + bs[j0]);
        float c1 = tanh_(a0[j0+1] + bs[j0+1]);
        A.out[(size_t)(base_nb+o  )*HW + pix] = (1.f-u0)*h0 + u0*c0;
        A.out[(size_t)(base_nb+o+1)*HW + pix] = (1.f-u1)*h1 + u1*c1;
      }
    }
  }
}

// ===========================================================================
// Fused cooperative kernel: 768 blocks (3/CU), grid.sync between phases.
// ===========================================================================
__global__ __launch_bounds__(256, 3)
void k_fused(KArgs A)
{
  __shared__ __align__(16) unsigned short L[LDS_N];
  cg::grid_group grid = cg::this_grid();

  for (int item = blockIdx.x; item < 1536; item += 768){
    __syncthreads();
    phaseA_att(A, L, item);
  }
  grid.sync();
  for (int item = blockIdx.x; item < 1024; item += 768){
    __syncthreads();
    phaseB_proj(A, L, item);
  }
  grid.sync();
  phaseC_gates(A, L, blockIdx.x);
  grid.sync();
  phaseD_out(A, L, blockIdx.x);
}

// ===========================================================================
// Fallback standalone kernels (round-16 proven path)
// ===========================================================================
__global__ __launch_bounds__(256)
void k_att_dec(KArgs A)
{
  __shared__ __align__(16) unsigned short L[13440];
  phaseA_att(A, L, (int)blockIdx.x);
}
__global__ __launch_bounds__(256, 2)
void k_proj(KArgs A)
{
  __shared__ __align__(16) unsigned short L[16896];
  phaseB_proj(A, L, (int)blockIdx.x);
}
__global__ __launch_bounds__(256, 3)
void k_gru_gates(KArgs A)
{
  __shared__ __align__(16) unsigned short L[LDS_N];
  phaseC_gates(A, L, (int)blockIdx.x);
}
__global__ __launch_bounds__(256, 3)
void k_gru_out(KArgs A)
{
  __shared__ __align__(16) unsigned short L[T6_N + WC_ELEMS];
  phaseD_out(A, L, (int)blockIdx.x);
}

// ---------------------------------------------------------------------------
extern "C" void kernel_launch(void* const* d_in, const int* in_sizes, int n_in,
                              void* d_out, int out_size, void* d_ws, size_t ws_size,
                              hipStream_t stream)
{
  (void)in_sizes; (void)n_in; (void)out_size; (void)ws_size;
  float* wsf = (float*)d_ws;

  KArgs ka;
  ka.hn   = (const float*)d_in[1];
  ka.pnn  = (const float*)d_in[2];
  ka.xp   = (const float*)d_in[3];
  ka.Wdau = (const float*)d_in[4];
  ka.bdau = (const float*)d_in[5];
  ka.Wdal = (const float*)d_in[6];
  ka.bdal = (const float*)d_in[7];
  ka.Wd1  = (const float*)d_in[8];
  ka.s1v  = (const float*)d_in[9];
  ka.t1v  = (const float*)d_in[10];
  ka.Wd2  = (const float*)d_in[11];
  ka.s2v  = (const float*)d_in[12];
  ka.t2v  = (const float*)d_in[13];
  ka.Wa0  = (const float*)d_in[14];
  ka.Wa1  = (const float*)d_in[15];
  ka.Wa2  = (const float*)d_in[16];
  ka.Wa3  = (const float*)d_in[17];
  ka.Wa4  = (const float*)d_in[18];
  ka.Wa5  = (const float*)d_in[19];
  ka.batt = (const float*)d_in[20];
  ka.Wp   = (const float*)d_in[21];
  ka.ps   = (const float*)d_in[22];
  ka.pt   = (const float*)d_in[23];
  ka.Wg   = (const float*)d_in[24];
  ka.bg   = (const float*)d_in[25];
  ka.Wc   = (const float*)d_in[26];
  ka.bc   = (const float*)d_in[27];
  ka.out  = (float*)d_out;
  ka.msg  = (unsigned*)wsf;
  ka.rh   = (unsigned*)(wsf + 1966080);
  ka.u    = (unsigned*)(wsf + 3932160);

  void* args[] = { &ka };
  hipError_t err = hipLaunchCooperativeKernel((const void*)k_fused,
                                              dim3(768), dim3(256), args, 0, stream);
  if (err != hipSuccess){
    // fallback: proven 4-kernel path (round 16)
    k_att_dec  <<<dim3(1536), dim3(256), 0, stream>>>(ka);
    k_proj     <<<dim3(1024), dim3(256), 0, stream>>>(ka);
    k_gru_gates<<<dim3(768),  dim3(256), 0, stream>>>(ka);
    k_gru_out  <<<dim3(768),  dim3(256), 0, stream>>>(ka);
  }
}

// Round 18
// 84.955 us; speedup vs baseline: 4.5820x; 4.5820x over previous
//
#include <hip/hip_runtime.h>
#include <math.h>

#define HW    16384
#define WID   128
#define NB    4
// output section offsets (floats)
#define OFF_U 3932160
#define OFF_L 4259840
#define OFF_F 4456448

// conv tile geometry (ch-interleaved bf16): [6 rows][132 x][24 ch]
#define TCH   24
#define TROW  132
#define T6_N  (6*TROW*TCH)        // 19008 shorts = 38.0 KB
#define WG_ELEMS   (9*32*TCH)     // 6912 shorts  = 13.8 KB
#define WC_ELEMS   (9*16*TCH)     // 3456 shorts  =  6.9 KB

typedef __attribute__((ext_vector_type(8))) short  short8_t;
typedef __attribute__((ext_vector_type(4))) float  float4_t;

__device__ __forceinline__ float sig_(float x)  { return 1.f/(1.f+__expf(-x)); }
__device__ __forceinline__ float tanh_(float x) { float e=__expf(2.f*x); return 1.f - 2.f/(e+1.f); }
// HW packed fp32->bf16 pair (dst.lo = bf16(a), dst.hi = bf16(b))
__device__ __forceinline__ unsigned pk2bf(float a, float b){
  unsigned r;
  asm("v_cvt_pk_bf16_f32 %0, %1, %2" : "=v"(r) : "v"(a), "v"(b));
  return r;
}
__device__ __forceinline__ float bf2f(unsigned short s){
  return __uint_as_float(((unsigned)s) << 16);
}
// XCD-aware bijective swizzles
__device__ __forceinline__ int swz1536(int bi){ return (bi & 7)*192 + (bi >> 3); }
__device__ __forceinline__ int swz768 (int bi){ return (bi & 7)*96  + (bi >> 3); }

// ---------------------------------------------------------------------------
// Kernel A v2: node-split + XCD swizzle; relation as 2-stage MFMA GEMM.
// ---------------------------------------------------------------------------
__global__ __launch_bounds__(256)
void k_att_dec(const float* __restrict__ hn, const float* __restrict__ pnn,
               const float* __restrict__ Wdau, const float* __restrict__ bdau,
               const float* __restrict__ Wdal, const float* __restrict__ bdal,
               const float* __restrict__ Wd1, const float* __restrict__ s1v, const float* __restrict__ t1v,
               const float* __restrict__ Wd2, const float* __restrict__ s2v, const float* __restrict__ t2v,
               const float* __restrict__ Wa0, const float* __restrict__ Wa1, const float* __restrict__ Wa2,
               const float* __restrict__ Wa3, const float* __restrict__ Wa4, const float* __restrict__ Wa5,
               const float* __restrict__ batt,
               float* __restrict__ out, unsigned* __restrict__ wmsg_p)
{
  __shared__ __align__(16) unsigned short xl [256*TCH];
  __shared__ __align__(16) unsigned short hl [256*TCH];
  __shared__ __align__(16) unsigned short wl1[32*TCH];
  __shared__ __align__(16) unsigned short wl2[16*TCH];

  const int bi    = swz1536(blockIdx.x);
  const int n     = bi >> 8;
  const int chunk = bi & 255;
  const int b     = chunk >> 6;
  const int pixbase = (chunk & 63) * 256;
  const int tid   = threadIdx.x;
  const int pix   = pixbase + tid;

  short8_t zz = {0,0,0,0,0,0,0,0};
#pragma unroll
  for (int it=0; it<3; ++it) *reinterpret_cast<short8_t*>(&xl[tid*8 + it*2048]) = zz;
#pragma unroll
  for (int it=0; it<3; ++it) *reinterpret_cast<short8_t*>(&hl[tid*8 + it*2048]) = zz;
  if (tid < 96)  *reinterpret_cast<short8_t*>(&wl1[tid*8]) = zz;
  if (tid < 48)  *reinterpret_cast<short8_t*>(&wl2[tid*8]) = zz;
  __syncthreads();

  if (tid < 200){
    int o = tid/10, chp = tid - o*10;
    float s = s1v[o];
    *reinterpret_cast<unsigned*>(&wl1[o*TCH + 2*chp]) =
        pk2bf(Wd1[o*20 + 2*chp]*s, Wd1[o*20 + 2*chp+1]*s);
  } else if (tid < 300){
    int e = tid - 200;
    int o = e/10, chp = e - o*10;
    float s = s2v[o];
    *reinterpret_cast<unsigned*>(&wl2[o*TCH + 2*chp]) =
        pk2bf(Wd2[o*20 + 2*chp]*s, Wd2[o*20 + 2*chp+1]*s);
  }

  float h[10];
  float a;
  if (n < 4){
#pragma unroll
    for (int c=0;c<10;c++) h[c] = hn[(b*10+c)*HW + pix];
    float v[5]; float mx = -1e30f;
#pragma unroll
    for (int o=0;o<5;o++){
      float t = bdau[o];
#pragma unroll
      for (int c=0;c<10;c++) t += Wdau[o*10+c]*h[c];
      if (n==0) out[OFF_U + (b*5+o)*HW + pix] = t;
      v[o]=t; mx = fmaxf(mx,t);
    }
    float s=0.f;
#pragma unroll
    for (int o=0;o<5;o++){ v[o]=__expf(v[o]-mx); s+=v[o]; }
    a = v[n+1]/s;
  } else {
#pragma unroll
    for (int c=0;c<10;c++) h[c] = hn[((NB+b)*10+c)*HW + pix];
    float v[3]; float mx = -1e30f;
#pragma unroll
    for (int o=0;o<3;o++){
      float t = bdal[o];
#pragma unroll
      for (int c=0;c<10;c++) t += Wdal[o*10+c]*h[c];
      if (n==4) out[OFF_L + (b*3+o)*HW + pix] = t;
      v[o]=t; mx = fmaxf(mx,t);
    }
    float s=0.f;
#pragma unroll
    for (int o=0;o<3;o++){ v[o]=__expf(v[o]-mx); s+=v[o]; }
    a = v[n-3]/s;
  }

  float child[10];
#pragma unroll
  for (int c=0;c<10;c++) child[c] = pnn[((n*NB+b)*10+c)*HW + pix];

  float af = batt[n];
  if (n==0){
#pragma unroll
    for (int c=0;c<10;c++) af += Wa0[c]*pnn[((1*NB+b)*10+c)*HW+pix];
  } else if (n==1){
#pragma unroll
    for (int c=0;c<10;c++){
      af += Wa1[c]   *pnn[((0*NB+b)*10+c)*HW+pix];
      af += Wa1[10+c]*pnn[((2*NB+b)*10+c)*HW+pix];
      af += Wa1[20+c]*pnn[((3*NB+b)*10+c)*HW+pix];
      af += Wa1[30+c]*pnn[((4*NB+b)*10+c)*HW+pix];
    }
  } else if (n==2){
#pragma unroll
    for (int c=0;c<10;c++) af += Wa2[c]*pnn[((1*NB+b)*10+c)*HW+pix];
  } else if (n==3){
#pragma unroll
    for (int c=0;c<10;c++) af += Wa3[c]*pnn[((1*NB+b)*10+c)*HW+pix];
  } else if (n==4){
#pragma unroll
    for (int c=0;c<10;c++){
      af += Wa4[c]   *pnn[((1*NB+b)*10+c)*HW+pix];
      af += Wa4[10+c]*pnn[((5*NB+b)*10+c)*HW+pix];
    }
  } else {
#pragma unroll
    for (int c=0;c<10;c++) af += Wa5[c]*pnn[((4*NB+b)*10+c)*HW+pix];
  }
  out[OFF_F + (n*NB+b)*HW + pix] = sig_(af);

#pragma unroll
  for (int p=0;p<5;p++)
    *reinterpret_cast<unsigned*>(&xl[tid*TCH + 2*p])      = pk2bf(h[2*p]*a, h[2*p+1]*a);
#pragma unroll
  for (int p=0;p<5;p++)
    *reinterpret_cast<unsigned*>(&xl[tid*TCH + 10 + 2*p]) = pk2bf(child[2*p], child[2*p+1]);
  __syncthreads();

  const int l  = tid & 63;
  const int w  = tid >> 6;
  const int lr = l & 15;
  const int lk = l >> 4;

  short8_t wa0 = (lk<3) ? *reinterpret_cast<const short8_t*>(&wl1[lr*TCH      + lk*8]) : zz;
  short8_t wa1 = (lk<3) ? *reinterpret_cast<const short8_t*>(&wl1[(16+lr)*TCH + lk*8]) : zz;
  float t1a[4], t1b[4];
#pragma unroll
  for (int j=0;j<4;j++){
    t1a[j] = t1v[lk*4 + j];
    int o1 = 16 + lk*4 + j;
    t1b[j] = (o1 < 20) ? t1v[o1] : 0.f;
  }

#pragma unroll
  for (int t=0; t<4; ++t){
    const int tile = w*4 + t;
    short8_t bf = (lk<3) ? *reinterpret_cast<const short8_t*>(&xl[(tile*16+lr)*TCH + lk*8]) : zz;
    float4_t a0 = {0.f,0.f,0.f,0.f}, a1 = {0.f,0.f,0.f,0.f};
    a0 = __builtin_amdgcn_mfma_f32_16x16x32_bf16(wa0, bf, a0, 0,0,0);
    a1 = __builtin_amdgcn_mfma_f32_16x16x32_bf16(wa1, bf, a1, 0,0,0);
    const int rowb = (tile*16+lr)*TCH;
#pragma unroll
    for (int jp=0; jp<2; ++jp){
      float v0 = fmaxf(a0[2*jp]   + t1a[2*jp],   0.f);
      float v1 = fmaxf(a0[2*jp+1] + t1a[2*jp+1], 0.f);
      *reinterpret_cast<unsigned*>(&hl[rowb + lk*4 + 2*jp]) = pk2bf(v0, v1);
    }
    if (lk == 0){
#pragma unroll
      for (int jp=0; jp<2; ++jp){
        float v0 = fmaxf(a1[2*jp]   + t1b[2*jp],   0.f);
        float v1 = fmaxf(a1[2*jp+1] + t1b[2*jp+1], 0.f);
        *reinterpret_cast<unsigned*>(&hl[rowb + 16 + 2*jp]) = pk2bf(v0, v1);
      }
    }
  }
  __syncthreads();

  short8_t wa2 = (lk<3) ? *reinterpret_cast<const short8_t*>(&wl2[lr*TCH + lk*8]) : zz;
  float t2a[4];
#pragma unroll
  for (int j=0;j<4;j++){
    int o = lk*4 + j;
    t2a[j] = (o < 10) ? t2v[o] : 0.f;
  }

#pragma unroll
  for (int t=0; t<4; ++t){
    const int tile = w*4 + t;
    short8_t bf = (lk<3) ? *reinterpret_cast<const short8_t*>(&hl[(tile*16+lr)*TCH + lk*8]) : zz;
    float4_t c = {0.f,0.f,0.f,0.f};
    c = __builtin_amdgcn_mfma_f32_16x16x32_bf16(wa2, bf, c, 0,0,0);
    const int pixT = pixbase + tile*16 + lr;
#pragma unroll
    for (int jp=0; jp<2; ++jp){
      const int o0 = lk*4 + 2*jp;
      if (o0 < 10){
        float v0 = fmaxf(c[2*jp]   + t2a[2*jp],   0.f);
        float v1 = fmaxf(c[2*jp+1] + t2a[2*jp+1], 0.f);
        wmsg_p[((size_t)((n*NB+b)*5 + (o0>>1)))*HW + pixT] = pk2bf(v0, v1);
      }
    }
  }
}

// ---------------------------------------------------------------------------
// Kernel B: projection GEMM v3 with packed-bf16 RMW epilogue
// ---------------------------------------------------------------------------
__global__ __launch_bounds__(256, 2)
void k_proj(const float* __restrict__ xp, const float* __restrict__ Wp,
            const float* __restrict__ ps, const float* __restrict__ pt,
            const float* __restrict__ outf, unsigned* __restrict__ wmsg_p)
{
  __shared__ __align__(16) unsigned short wlds[64*264];
  const int tid = threadIdx.x;

#pragma unroll
  for (int it=0; it<16; ++it){
    const int e = tid + it*256;
    const int row = e >> 6, q = e & 63;
    uint2 pk; pk.x = 0u; pk.y = 0u;
    if (row < 60){
      const float s = ps[row];
      float4 wv = *reinterpret_cast<const float4*>(Wp + row*256 + q*4);
      pk.x = pk2bf(wv.x*s, wv.y*s);
      pk.y = pk2bf(wv.z*s, wv.w*s);
    }
    *reinterpret_cast<uint2*>(&wlds[row*264 + q*4]) = pk;
  }
  __syncthreads();

  const int l  = tid & 63;
  const int w  = tid >> 6;
  const int lr = l & 15;
  const int lk = l >> 4;

  const int tile = blockIdx.x*4 + w;
  const int P    = tile*16;
  const int b    = P >> 14;
  const int pixb = P & 16383;
  const int px   = pixb + lr;

  const float* xb = xp + (size_t)(b*256)*HW + px;
  float v[64];
#pragma unroll
  for (int ks=0; ks<8; ++ks)
#pragma unroll
    for (int j=0; j<8; ++j)
      v[ks*8+j] = xb[(size_t)(ks*32 + lk*8 + j)*HW];

  short8_t bf[8];
#pragma unroll
  for (int ks=0; ks<8; ++ks){
    union { short8_t s; unsigned u[4]; } bu;
#pragma unroll
    for (int jp=0; jp<4; ++jp)
      bu.u[jp] = pk2bf(v[ks*8+2*jp], v[ks*8+2*jp+1]);
    bf[ks] = bu.s;
  }

  float4_t acc[4];
#pragma unroll
  for (int nf=0;nf<4;nf++){ acc[nf][0]=0.f; acc[nf][1]=0.f; acc[nf][2]=0.f; acc[nf][3]=0.f; }

#pragma unroll
  for (int ks=0; ks<8; ++ks){
#pragma unroll
    for (int nf=0; nf<4; ++nf){
      short8_t wa = *reinterpret_cast<const short8_t*>(&wlds[(nf*16+lr)*264 + ks*32 + lk*8]);
      acc[nf] = __builtin_amdgcn_mfma_f32_16x16x32_bf16(wa, bf[ks], acc[nf], 0,0,0);
    }
  }

#pragma unroll
  for (int nf=0;nf<4;nf++){
#pragma unroll
    for (int jp=0;jp<2;jp++){
      const int row0 = nf*16 + lk*4 + 2*jp;       // even
      if (row0 < 60){
        const unsigned nn = (unsigned)row0 / 10u;
        const int o = row0 - (int)nn*10;          // even, o+1 same node
        float att = outf[OFF_F + (nn*NB+b)*HW + pixb + lr];
        float f   = 2.f - att;
        float v0 = fmaxf(f*acc[nf][2*jp]   + pt[row0],   0.f);
        float v1 = fmaxf(f*acc[nf][2*jp+1] + pt[row0+1], 0.f);
        size_t idx = ((size_t)((nn*NB+b)*5 + (o>>1)))*HW + pixb + lr;
        unsigned old = wmsg_p[idx];
        float d0 = bf2f((unsigned short)(old & 0xffffu)) + v0;
        float d1 = bf2f((unsigned short)(old >> 16))     + v1;
        wmsg_p[idx] = pk2bf(d0, d1);
      }
    }
  }
}

// ---------------------------------------------------------------------------
// Kernel C: GRU gates conv, 4-row tiles + XCD swizzle; packed msg/rh/u
// ---------------------------------------------------------------------------
__global__ __launch_bounds__(256, 3)
void k_gru_gates(const float* __restrict__ pnn, const float* __restrict__ Wg,
                 const float* __restrict__ bg,
                 const unsigned* __restrict__ wmsg_p, unsigned* __restrict__ wrh_p,
                 unsigned* __restrict__ wu_p)
{
  __shared__ __align__(16) unsigned short tl[T6_N];
  __shared__ __align__(16) unsigned short wl[WG_ELEMS];
  const int bi = swz768(blockIdx.x);
  const int n  = bi >> 7;
  const int b  = (bi >> 5) & 3;
  const int y0 = (bi & 31) * 4;
  const int tid = threadIdx.x;

  const int base_nb  = (n*NB+b)*10;
  const int base_nb5 = (n*NB+b)*5;
  const float* pb = pnn + (size_t)base_nb*HW;

  short8_t zz = {0,0,0,0,0,0,0,0};
#pragma unroll
  for (int it=0; it<10; ++it){
    const int e = tid*8 + it*2048;
    if (e < T6_N) *reinterpret_cast<short8_t*>(&tl[e]) = zz;
  }
#pragma unroll
  for (int it=0; it<4; ++it){
    const int e = tid*8 + it*2048;
    if (e < WG_ELEMS) *reinterpret_cast<short8_t*>(&wl[e]) = zz;
  }
  __syncthreads();

  const float* Wn = Wg + n*3600;
#pragma unroll
  for (int it=0; it<8; ++it){
    const int e = tid + it*256;
    if (e < 1800){
      int sh = e/200, rem = e - sh*200, o = rem/10, chp = rem - o*10;
      float w0 = Wn[o*180 + (2*chp  )*9 + sh];
      float w1 = Wn[o*180 + (2*chp+1)*9 + sh];
      *reinterpret_cast<unsigned*>(&wl[(sh*32+o)*TCH + 2*chp]) = pk2bf(w0, w1);
    }
  }
#pragma unroll
  for (int it=0; it<30; ++it){
    const int e = tid + it*256;
    int row = e/1280, rem = e - row*1280, chp = rem>>7, x = rem&127;
    int yy = y0 - 1 + row;
    if ((unsigned)yy < 128u){
      unsigned pk;
      if (chp < 5){
        pk = wmsg_p[((size_t)(base_nb5 + chp))*HW + yy*WID + x];
      } else {
        const float* s0 = pb + (size_t)(2*chp-10)*HW;
        pk = pk2bf(s0[yy*WID + x], s0[HW + yy*WID + x]);
      }
      *reinterpret_cast<unsigned*>(&tl[(row*TROW + x+1)*TCH + 2*chp]) = pk;
    }
  }
  __syncthreads();

  const int l  = tid & 63;
  const int w  = tid >> 6;
  const int lr = l & 15;
  const int lk = l >> 4;

  short8_t wa0[9], wa1[9];
#pragma unroll
  for (int sh=0; sh<9; sh++){
    wa0[sh] = (lk<3) ? *reinterpret_cast<const short8_t*>(&wl[(sh*32 +      lr)*TCH + lk*8]) : zz;
    wa1[sh] = (lk<3) ? *reinterpret_cast<const short8_t*>(&wl[(sh*32 + 16 + lr)*TCH + lk*8]) : zz;
  }
  float bs0[4], bs1[4];
#pragma unroll
  for (int j=0;j<4;j++){
    int o = lk*4 + j;
    bs0[j] = bg[n*20 + o];
    int o1 = 16 + lk*4 + j;
    bs1[j] = (o1 < 20) ? bg[n*20 + o1] : 0.f;
  }

  for (int t=0; t<8; ++t){
    const int tile  = w*8 + t;
    const int row_t = tile >> 3;          // 0..3
    const int xloc  = (tile & 7) * 16;

    float4_t a0 = {0.f,0.f,0.f,0.f}, a1 = {0.f,0.f,0.f,0.f};
#pragma unroll
    for (int sh=0; sh<9; sh++){
      const int dy = sh/3, dx = sh - dy*3;
      const int addr = ((row_t + dy)*TROW + (xloc + lr + dx))*TCH + lk*8;
      short8_t bf = (lk<3) ? *reinterpret_cast<const short8_t*>(&tl[addr]) : zz;
      a0 = __builtin_amdgcn_mfma_f32_16x16x32_bf16(wa0[sh], bf, a0, 0,0,0);
      a1 = __builtin_amdgcn_mfma_f32_16x16x32_bf16(wa1[sh], bf, a1, 0,0,0);
    }

    const int pix = (y0 + row_t)*WID + xloc + lr;
#pragma unroll
    for (int jp=0; jp<2; ++jp){
      const int j0 = 2*jp;
      const int o  = lk*4 + j0;
      float g0 = sig_(a0[j0]   + bs0[j0]);
      float g1 = sig_(a0[j0+1] + bs0[j0+1]);
      if (o < 10){
        float h0 = pb[(size_t)o*HW + pix];
        float h1 = pb[(size_t)(o+1)*HW + pix];
        wrh_p[((size_t)(base_nb5 + (o>>1)))*HW + pix] = pk2bf(g0*h0, g1*h1);
      } else {
        wu_p[((size_t)(base_nb5 + ((o-10)>>1)))*HW + pix] = pk2bf(g0, g1);
      }
    }
    if (lk == 0){
#pragma unroll
      for (int jp=0; jp<2; ++jp){
        const int j0 = 2*jp;
        const int o1 = 16 + j0;                  // u ch 6..9
        float g0 = sig_(a1[j0]   + bs1[j0]);
        float g1 = sig_(a1[j0+1] + bs1[j0+1]);
        wu_p[((size_t)(base_nb5 + ((o1-10)>>1)))*HW + pix] = pk2bf(g0, g1);
      }
    }
  }
}

// ---------------------------------------------------------------------------
// Kernel D: candidate conv + GRU blend; packed msg/rh loads, packed u
// ---------------------------------------------------------------------------
__global__ __launch_bounds__(256, 3)
void k_gru_out(const float* __restrict__ pnn, const float* __restrict__ Wc,
               const float* __restrict__ bc,
               const unsigned* __restrict__ wmsg_p, const unsigned* __restrict__ wrh_p,
               const unsigned* __restrict__ wu_p, float* __restrict__ out)
{
  __shared__ __align__(16) unsigned short tl[T6_N];
  __shared__ __align__(16) unsigned short wl[WC_ELEMS];
  const int bi = swz768(blockIdx.x);
  const int n  = bi >> 7;
  const int b  = (bi >> 5) & 3;
  const int y0 = (bi & 31) * 4;
  const int tid = threadIdx.x;

  const int base_nb  = (n*NB+b)*10;
  const int base_nb5 = (n*NB+b)*5;
  const float* pb = pnn + (size_t)base_nb*HW;

  short8_t zz = {0,0,0,0,0,0,0,0};
#pragma unroll
  for (int it=0; it<10; ++it){
    const int e = tid*8 + it*2048;
    if (e < T6_N) *reinterpret_cast<short8_t*>(&tl[e]) = zz;
  }
#pragma unroll
  for (int it=0; it<2; ++it){
    const int e = tid*8 + it*2048;
    if (e < WC_ELEMS) *reinterpret_cast<short8_t*>(&wl[e]) = zz;
  }
  __syncthreads();

  const float* Wn = Wc + n*1800;
#pragma unroll
  for (int it=0; it<4; ++it){
    const int e = tid + it*256;
    if (e < 900){
      int sh = e/100, rem = e - sh*100, o = rem/10, chp = rem - o*10;
      float w0 = Wn[o*180 + (2*chp  )*9 + sh];
      float w1 = Wn[o*180 + (2*chp+1)*9 + sh];
      *reinterpret_cast<unsigned*>(&wl[(sh*16+o)*TCH + 2*chp]) = pk2bf(w0, w1);
    }
  }
#pragma unroll
  for (int it=0; it<30; ++it){
    const int e = tid + it*256;
    int row = e/1280, rem = e - row*1280, chp = rem>>7, x = rem&127;
    int yy = y0 - 1 + row;
    if ((unsigned)yy < 128u){
      unsigned pk;
      if (chp < 5){
        pk = wmsg_p[((size_t)(base_nb5 + chp))*HW + yy*WID + x];
      } else {
        pk = wrh_p[((size_t)(base_nb5 + (chp-5)))*HW + yy*WID + x];
      }
      *reinterpret_cast<unsigned*>(&tl[(row*TROW + x+1)*TCH + 2*chp]) = pk;
    }
  }
  __syncthreads();

  const int l  = tid & 63;
  const int w  = tid >> 6;
  const int lr = l & 15;
  const int lk = l >> 4;

  short8_t wa[9];
#pragma unroll
  for (int sh=0; sh<9; sh++)
    wa[sh] = (lk<3) ? *reinterpret_cast<const short8_t*>(&wl[(sh*16 + lr)*TCH + lk*8]) : zz;

  float bs[4];
#pragma unroll
  for (int j=0;j<4;j++){
    int o = lk*4 + j;
    bs[j] = (o < 10) ? bc[n*10 + o] : 0.f;
  }

  for (int t=0; t<8; ++t){
    const int tile  = w*8 + t;
    const int row_t = tile >> 3;
    const int xloc  = (tile & 7) * 16;

    float4_t a0 = {0.f,0.f,0.f,0.f};
#pragma unroll
    for (int sh=0; sh<9; sh++){
      const int dy = sh/3, dx = sh - dy*3;
      const int addr = ((row_t + dy)*TROW + (xloc + lr + dx))*TCH + lk*8;
      short8_t bf = (lk<3) ? *reinterpret_cast<const short8_t*>(&tl[addr]) : zz;
      a0 = __builtin_amdgcn_mfma_f32_16x16x32_bf16(wa[sh], bf, a0, 0,0,0);
    }

    const int pix = (y0 + row_t)*WID + xloc + lr;
#pragma unroll
    for (int jp=0; jp<2; ++jp){
      const int j0 = 2*jp;
      const int o  = lk*4 + j0;
      if (o < 10){
        unsigned up = wu_p[((size_t)(base_nb5 + (o>>1)))*HW + pix];
        float u0 = bf2f((unsigned short)(up & 0xffffu));
        float u1 = bf2f((unsigned short)(up >> 16));
        float h0 = pb[(size_t)o*HW + pix];
        float h1 = pb[(size_t)(o+1)*HW + pix];
        float c0 = tanh_(a0[j0]   + bs[j0]);
        float c1 = tanh_(a0[j0+1] + bs[j0+1]);
        out[(size_t)(base_nb+o  )*HW + pix] = (1.f-u0)*h0 + u0*c0;
        out[(size_t)(base_nb+o+1)*HW + pix] = (1.f-u1)*h1 + u1*c1;
      }
    }
  }
}

// ---------------------------------------------------------------------------
extern "C" void kernel_launch(void* const* d_in, const int* in_sizes, int n_in,
                              void* d_out, int out_size, void* d_ws, size_t ws_size,
                              hipStream_t stream)
{
  (void)in_sizes; (void)n_in; (void)out_size; (void)ws_size;
  const float* hn   = (const float*)d_in[1];
  const float* pnn  = (const float*)d_in[2];
  const float* xp   = (const float*)d_in[3];
  const float* Wdau = (const float*)d_in[4];
  const float* bdau = (const float*)d_in[5];
  const float* Wdal = (const float*)d_in[6];
  const float* bdal = (const float*)d_in[7];
  const float* Wd1  = (const float*)d_in[8];
  const float* s1v  = (const float*)d_in[9];
  const float* t1v  = (const float*)d_in[10];
  const float* Wd2  = (const float*)d_in[11];
  const float* s2v  = (const float*)d_in[12];
  const float* t2v  = (const float*)d_in[13];
  const float* Wa0  = (const float*)d_in[14];
  const float* Wa1  = (const float*)d_in[15];
  const float* Wa2  = (const float*)d_in[16];
  const float* Wa3  = (const float*)d_in[17];
  const float* Wa4  = (const float*)d_in[18];
  const float* Wa5  = (const float*)d_in[19];
  const float* batt = (const float*)d_in[20];
  const float* Wp   = (const float*)d_in[21];
  const float* ps   = (const float*)d_in[22];
  const float* pt   = (const float*)d_in[23];
  const float* Wg   = (const float*)d_in[24];
  const float* bg   = (const float*)d_in[25];
  const float* Wc   = (const float*)d_in[26];
  const float* bc   = (const float*)d_in[27];

  float* out = (float*)d_out;
  float* wsf = (float*)d_ws;
  unsigned* ws_msg = (unsigned*)wsf;                 // packed bf16 pairs [6*4*5*HW] u32
  unsigned* ws_rh  = (unsigned*)(wsf + 1966080);     // packed bf16 pairs [6*4*5*HW] u32
  unsigned* ws_u   = (unsigned*)(wsf + 3932160);     // packed bf16 pairs [6*4*5*HW] u32

  k_att_dec<<<dim3(1536), dim3(256), 0, stream>>>(hn, pnn, Wdau, bdau, Wdal, bdal,
      Wd1, s1v, t1v, Wd2, s2v, t2v, Wa0, Wa1, Wa2, Wa3, Wa4, Wa5, batt, out, ws_msg);
  k_proj<<<dim3(1024), dim3(256), 0, stream>>>(xp, Wp, ps, pt, (const float*)d_out, ws_msg);
  k_gru_gates<<<dim3(768), dim3(256), 0, stream>>>(pnn, Wg, bg, ws_msg, ws_rh, ws_u);
  k_gru_out<<<dim3(768), dim3(256), 0, stream>>>(pnn, Wc, bc, ws_msg, ws_rh, ws_u, out);
}